// Round 1
// baseline (663.700 us; speedup 1.0000x reference)
//
#include <hip/hip_runtime.h>

// Problem constants
#define NB 32
#define NNODES 1024
#define DD 256
#define KNB 64

// =====================================================================
// GEMM (NN): C[M,N] = A[M,K] @ B[K,N] + bias[N] (+ resid[M,N] if non-null)
// 128x128 tile, BK=16, 256 threads, 8x8 per thread, fp32.
// =====================================================================
__global__ __launch_bounds__(256) void gemm_nn(const float* __restrict__ A,
                                               const float* __restrict__ Bm,
                                               const float* __restrict__ bias,
                                               const float* __restrict__ resid,
                                               float* __restrict__ C,
                                               int M, int Nn, int Kd) {
  __shared__ float As[16][132];  // transposed A tile: As[k][r], padded to 132
  __shared__ float Bs[16][128];  // B tile: Bs[k][c]
  const int tid = threadIdx.x;
  const int tx = tid & 15, ty = tid >> 4;
  const int r0 = blockIdx.y * 128, c0 = blockIdx.x * 128;
  const int ar = tid >> 2, ak = (tid & 3) * 4;   // A staging: row ar/ar+64, cols ak..ak+3
  const int bk = tid >> 5, bc = (tid & 31) * 4;  // B staging: row bk/bk+8, cols bc..bc+3

  float acc[8][8];
#pragma unroll
  for (int i = 0; i < 8; ++i)
#pragma unroll
    for (int j = 0; j < 8; ++j) acc[i][j] = 0.0f;

  for (int k0 = 0; k0 < Kd; k0 += 16) {
    float4 a0 = *(const float4*)(A + (size_t)(r0 + ar) * Kd + k0 + ak);
    float4 a1 = *(const float4*)(A + (size_t)(r0 + ar + 64) * Kd + k0 + ak);
    float4 b0 = *(const float4*)(Bm + (size_t)(k0 + bk) * Nn + c0 + bc);
    float4 b1 = *(const float4*)(Bm + (size_t)(k0 + bk + 8) * Nn + c0 + bc);
    __syncthreads();
    As[ak + 0][ar] = a0.x; As[ak + 1][ar] = a0.y; As[ak + 2][ar] = a0.z; As[ak + 3][ar] = a0.w;
    As[ak + 0][ar + 64] = a1.x; As[ak + 1][ar + 64] = a1.y; As[ak + 2][ar + 64] = a1.z; As[ak + 3][ar + 64] = a1.w;
    *(float4*)&Bs[bk][bc] = b0;
    *(float4*)&Bs[bk + 8][bc] = b1;
    __syncthreads();
#pragma unroll
    for (int kk = 0; kk < 16; ++kk) {
      float4 av0 = *(const float4*)&As[kk][ty * 4];
      float4 av1 = *(const float4*)&As[kk][64 + ty * 4];
      float4 bv0 = *(const float4*)&Bs[kk][tx * 4];
      float4 bv1 = *(const float4*)&Bs[kk][64 + tx * 4];
      float a[8] = {av0.x, av0.y, av0.z, av0.w, av1.x, av1.y, av1.z, av1.w};
      float bb[8] = {bv0.x, bv0.y, bv0.z, bv0.w, bv1.x, bv1.y, bv1.z, bv1.w};
#pragma unroll
      for (int i = 0; i < 8; ++i)
#pragma unroll
        for (int j = 0; j < 8; ++j) acc[i][j] = fmaf(a[i], bb[j], acc[i][j]);
    }
  }

  float4 bia0 = *(const float4*)(bias + c0 + tx * 4);
  float4 bia1 = *(const float4*)(bias + c0 + 64 + tx * 4);
#pragma unroll
  for (int i = 0; i < 8; ++i) {
    const int r = r0 + ((i < 4) ? (ty * 4 + i) : (64 + ty * 4 + (i - 4)));
    float* crow = C + (size_t)r * Nn;
    float4 o0, o1;
    o0.x = acc[i][0] + bia0.x; o0.y = acc[i][1] + bia0.y;
    o0.z = acc[i][2] + bia0.z; o0.w = acc[i][3] + bia0.w;
    o1.x = acc[i][4] + bia1.x; o1.y = acc[i][5] + bia1.y;
    o1.z = acc[i][6] + bia1.z; o1.w = acc[i][7] + bia1.w;
    if (resid) {
      const float* rrow = resid + (size_t)r * Nn;
      float4 rv0 = *(const float4*)(rrow + c0 + tx * 4);
      float4 rv1 = *(const float4*)(rrow + c0 + 64 + tx * 4);
      o0.x += rv0.x; o0.y += rv0.y; o0.z += rv0.z; o0.w += rv0.w;
      o1.x += rv1.x; o1.y += rv1.y; o1.z += rv1.z; o1.w += rv1.w;
    }
    *(float4*)(crow + c0 + tx * 4) = o0;
    *(float4*)(crow + c0 + 64 + tx * 4) = o1;
  }
}

// =====================================================================
// Scores (NT): S[b,m,n] = (Q[b,m,:] . K[b,n,:]) / 16 + adj[m,n]
// Same tiling as gemm_nn; both operands staged transposed.
// =====================================================================
__global__ __launch_bounds__(256) void scores_kernel(const float* __restrict__ Q,
                                                     const float* __restrict__ K,
                                                     const float* __restrict__ adj,
                                                     float* __restrict__ S) {
  __shared__ float Qs[16][132];
  __shared__ float Ks[16][132];
  const int tid = threadIdx.x;
  const int tx = tid & 15, ty = tid >> 4;
  const int b = blockIdx.z;
  const int m0 = blockIdx.y * 128, n0 = blockIdx.x * 128;
  const float* Qb = Q + (size_t)b * NNODES * DD;
  const float* Kb = K + (size_t)b * NNODES * DD;
  const int ar = tid >> 2, ak = (tid & 3) * 4;

  float acc[8][8];
#pragma unroll
  for (int i = 0; i < 8; ++i)
#pragma unroll
    for (int j = 0; j < 8; ++j) acc[i][j] = 0.0f;

  for (int d0 = 0; d0 < DD; d0 += 16) {
    float4 q0 = *(const float4*)(Qb + (size_t)(m0 + ar) * DD + d0 + ak);
    float4 q1 = *(const float4*)(Qb + (size_t)(m0 + ar + 64) * DD + d0 + ak);
    float4 k0v = *(const float4*)(Kb + (size_t)(n0 + ar) * DD + d0 + ak);
    float4 k1v = *(const float4*)(Kb + (size_t)(n0 + ar + 64) * DD + d0 + ak);
    __syncthreads();
    Qs[ak + 0][ar] = q0.x; Qs[ak + 1][ar] = q0.y; Qs[ak + 2][ar] = q0.z; Qs[ak + 3][ar] = q0.w;
    Qs[ak + 0][ar + 64] = q1.x; Qs[ak + 1][ar + 64] = q1.y; Qs[ak + 2][ar + 64] = q1.z; Qs[ak + 3][ar + 64] = q1.w;
    Ks[ak + 0][ar] = k0v.x; Ks[ak + 1][ar] = k0v.y; Ks[ak + 2][ar] = k0v.z; Ks[ak + 3][ar] = k0v.w;
    Ks[ak + 0][ar + 64] = k1v.x; Ks[ak + 1][ar + 64] = k1v.y; Ks[ak + 2][ar + 64] = k1v.z; Ks[ak + 3][ar + 64] = k1v.w;
    __syncthreads();
#pragma unroll
    for (int kk = 0; kk < 16; ++kk) {
      float4 av0 = *(const float4*)&Qs[kk][ty * 4];
      float4 av1 = *(const float4*)&Qs[kk][64 + ty * 4];
      float4 bv0 = *(const float4*)&Ks[kk][tx * 4];
      float4 bv1 = *(const float4*)&Ks[kk][64 + tx * 4];
      float a[8] = {av0.x, av0.y, av0.z, av0.w, av1.x, av1.y, av1.z, av1.w};
      float bb[8] = {bv0.x, bv0.y, bv0.z, bv0.w, bv1.x, bv1.y, bv1.z, bv1.w};
#pragma unroll
      for (int i = 0; i < 8; ++i)
#pragma unroll
        for (int j = 0; j < 8; ++j) acc[i][j] = fmaf(a[i], bb[j], acc[i][j]);
    }
  }

#pragma unroll
  for (int i = 0; i < 8; ++i) {
    const int m = m0 + ((i < 4) ? (ty * 4 + i) : (64 + ty * 4 + (i - 4)));
    const float4 ad0 = *(const float4*)(adj + (size_t)m * NNODES + n0 + tx * 4);
    const float4 ad1 = *(const float4*)(adj + (size_t)m * NNODES + n0 + 64 + tx * 4);
    float4 o0, o1;
    o0.x = acc[i][0] * 0.0625f + ad0.x; o0.y = acc[i][1] * 0.0625f + ad0.y;
    o0.z = acc[i][2] * 0.0625f + ad0.z; o0.w = acc[i][3] * 0.0625f + ad0.w;
    o1.x = acc[i][4] * 0.0625f + ad1.x; o1.y = acc[i][5] * 0.0625f + ad1.y;
    o1.z = acc[i][6] * 0.0625f + ad1.z; o1.w = acc[i][7] * 0.0625f + ad1.w;
    float* srow = S + ((size_t)b * NNODES + m) * NNODES;
    *(float4*)(srow + n0 + tx * 4) = o0;
    *(float4*)(srow + n0 + 64 + tx * 4) = o1;
  }
}

// =====================================================================
// Top-64 (exact, jax tie semantics: lowest index wins among equals) +
// masked softmax (in-place S -> attn) + sparse messages M = attn @ V.
// One wave per row; 4 rows per 256-thread block.
// =====================================================================
__global__ __launch_bounds__(256) void topk_softmax_msg(float* __restrict__ S,
                                                        const float* __restrict__ V,
                                                        float* __restrict__ Mo) {
  const int tid = threadIdx.x;
  const int w = tid >> 6, lane = tid & 63;
  const int row = blockIdx.x * 4 + w;  // 0..32767
  const int b = row >> 10;
  float* Srow = S + (size_t)row * NNODES;

  float s[16];
  unsigned key[16];
#pragma unroll
  for (int i = 0; i < 16; ++i) {
    float v = Srow[i * 64 + lane];
    s[i] = v;
    unsigned bits = __float_as_uint(v);
    key[i] = (bits & 0x80000000u) ? ~bits : (bits | 0x80000000u);
  }

  // 64th-largest key: MSB-first greedy search (monotone predicate count(>=T)>=64)
  unsigned cur = 0u;
#pragma unroll 1
  for (int bit = 31; bit >= 0; --bit) {
    const unsigned cand = cur | (1u << bit);
    int cnt = 0;
#pragma unroll
    for (int i = 0; i < 16; ++i) cnt += (key[i] >= cand) ? 1 : 0;
#pragma unroll
    for (int off = 32; off > 0; off >>= 1) cnt += __shfl_xor(cnt, off);
    if (cnt >= KNB) cur = cand;
  }

  // strictly-greater count -> how many ties to take (in index order)
  int cg = 0;
#pragma unroll
  for (int i = 0; i < 16; ++i) cg += (key[i] > cur) ? 1 : 0;
#pragma unroll
  for (int off = 32; off > 0; off >>= 1) cg += __shfl_xor(cg, off);
  const int m_eq = KNB - cg;

  const unsigned long long ltmask = (1ull << lane) - 1ull;
  int run = 0;
  unsigned selmask = 0;
#pragma unroll
  for (int i = 0; i < 16; ++i) {
    const bool eq = (key[i] == cur);
    const unsigned long long bal = __ballot(eq);
    const bool sel = (key[i] > cur) || (eq && (run + (int)__popcll(bal & ltmask)) < m_eq);
    run += (int)__popcll(bal);
    if (sel) selmask |= (1u << i);
  }

  // row max (top-1 is always selected, so max over all == max over selected)
  float rmax = s[0];
#pragma unroll
  for (int i = 1; i < 16; ++i) rmax = fmaxf(rmax, s[i]);
#pragma unroll
  for (int off = 32; off > 0; off >>= 1) rmax = fmaxf(rmax, __shfl_xor(rmax, off));

  float p[16];
  float sum = 0.0f;
#pragma unroll
  for (int i = 0; i < 16; ++i) {
    p[i] = __expf(s[i] - rmax);
    if ((selmask >> i) & 1u) sum += p[i];
  }
#pragma unroll
  for (int off = 32; off > 0; off >>= 1) sum += __shfl_xor(sum, off);
  const float inv = 1.0f / sum;

  // write attn row + compact selected (index-ordered, deterministic) into LDS
  __shared__ int sidx[4][KNB];
  __shared__ float swgt[4][KNB];
  int run2 = 0;
#pragma unroll
  for (int i = 0; i < 16; ++i) {
    const bool sel = (selmask >> i) & 1u;
    const unsigned long long bal = __ballot(sel);
    const float aw = sel ? p[i] * inv : 0.0f;
    Srow[i * 64 + lane] = aw;
    if (sel) {
      const int pos = run2 + (int)__popcll(bal & ltmask);
      sidx[w][pos] = i * 64 + lane;
      swgt[w][pos] = aw;
    }
    run2 += (int)__popcll(bal);
  }

  // messages: lane owns output dims [lane*4, lane*4+4)
  const float* Vb = V + (size_t)b * NNODES * DD;
  float4 acc = {0.0f, 0.0f, 0.0f, 0.0f};
  for (int t = 0; t < KNB; ++t) {
    const int j = sidx[w][t];
    const float wg = swgt[w][t];
    const float4 vv = *(const float4*)(Vb + (size_t)j * DD + lane * 4);
    acc.x = fmaf(wg, vv.x, acc.x);
    acc.y = fmaf(wg, vv.y, acc.y);
    acc.z = fmaf(wg, vv.z, acc.z);
    acc.w = fmaf(wg, vv.w, acc.w);
  }
  *(float4*)(Mo + (size_t)row * DD + lane * 4) = acc;
}

// =====================================================================
// LayerNorm + ReLU, in place. One 256-thread block per row of 256.
// =====================================================================
__global__ __launch_bounds__(256) void ln_relu(float* __restrict__ H,
                                               const float* __restrict__ g,
                                               const float* __restrict__ bta) {
  const int row = blockIdx.x;
  const int c = threadIdx.x;
  const int wv = c >> 6, ln = c & 63;
  float* hp = H + (size_t)row * DD;
  const float h = hp[c];

  __shared__ float part[4], part2[4];
  float v = h;
#pragma unroll
  for (int off = 32; off > 0; off >>= 1) v += __shfl_xor(v, off);
  if (ln == 0) part[wv] = v;
  __syncthreads();
  const float mu = (part[0] + part[1] + part[2] + part[3]) * (1.0f / 256.0f);

  const float d = h - mu;
  float sq = d * d;
#pragma unroll
  for (int off = 32; off > 0; off >>= 1) sq += __shfl_xor(sq, off);
  if (ln == 0) part2[wv] = sq;
  __syncthreads();
  const float var = (part2[0] + part2[1] + part2[2] + part2[3]) * (1.0f / 256.0f);

  const float y = d * (1.0f / sqrtf(var + 1e-5f)) * g[c] + bta[c];
  hp[c] = fmaxf(y, 0.0f);
}

// =====================================================================
// Host launch
// =====================================================================
extern "C" void kernel_launch(void* const* d_in, const int* in_sizes, int n_in,
                              void* d_out, int out_size, void* d_ws, size_t ws_size,
                              hipStream_t stream) {
  (void)in_sizes; (void)n_in; (void)out_size; (void)ws_size;
  const float* x   = (const float*)d_in[0];
  const float* wq  = (const float*)d_in[1];
  const float* bq  = (const float*)d_in[2];
  const float* wk  = (const float*)d_in[3];
  const float* bk  = (const float*)d_in[4];
  const float* wv  = (const float*)d_in[5];
  const float* bv  = (const float*)d_in[6];
  const float* adj = (const float*)d_in[7];
  const float* w1  = (const float*)d_in[8];
  const float* b1  = (const float*)d_in[9];
  const float* lng = (const float*)d_in[10];
  const float* lnb = (const float*)d_in[11];
  const float* w2  = (const float*)d_in[12];
  const float* b2  = (const float*)d_in[13];

  const size_t BN = (size_t)NB * NNODES;        // 32768
  const size_t BND = BN * DD;                   // 8,388,608 floats
  float* outp  = (float*)d_out;                 // [BN][256]
  float* attnp = outp + BND;                    // [BN][1024] (scratch: scores, then attn)

  float* Q = (float*)d_ws;                      // needs 3 * 33.5 MB of ws
  float* K = Q + BND;
  float* V = K + BND;
  float* M = Q;                                 // reuse (Q dead after scores)
  float* H = K;                                 // reuse (K dead after scores)

  const dim3 blk(256);
  const dim3 gemm_grid(DD / 128, BN / 128);     // (2, 256)

  // 1) Q, K, V projections
  gemm_nn<<<gemm_grid, blk, 0, stream>>>(x, wq, bq, nullptr, Q, (int)BN, DD, DD);
  gemm_nn<<<gemm_grid, blk, 0, stream>>>(x, wk, bk, nullptr, K, (int)BN, DD, DD);
  gemm_nn<<<gemm_grid, blk, 0, stream>>>(x, wv, bv, nullptr, V, (int)BN, DD, DD);

  // 2) scores -> attn scratch region of d_out
  scores_kernel<<<dim3(NNODES / 128, NNODES / 128, NB), blk, 0, stream>>>(Q, K, adj, attnp);

  // 3) exact top-64 + softmax (in place) + sparse messages
  topk_softmax_msg<<<dim3(BN / 4), blk, 0, stream>>>(attnp, V, M);

  // 4) MLP layer 1 + LayerNorm + ReLU
  gemm_nn<<<gemm_grid, blk, 0, stream>>>(M, w1, b1, nullptr, H, (int)BN, DD, DD);
  ln_relu<<<dim3((unsigned)BN), blk, 0, stream>>>(H, lng, lnb);

  // 5) MLP layer 2 + residual(V) -> out
  gemm_nn<<<gemm_grid, blk, 0, stream>>>(H, w2, b2, V, outp, (int)BN, DD, DD);
}

// Round 3
// 526.215 us; speedup vs baseline: 1.2613x; 1.2613x over previous
//
#include <hip/hip_runtime.h>
#include <cstdint>

#define NB 32
#define NNODES 1024
#define DD 256
#define KNB 64
#define MTOT (NB * NNODES)  // 32768

// Scaling: activations stored as split(64*a), weights as split(1024*w).
// acc = sum (64a)(1024w) = 65536 * a.w  -> epilogue * 1/65536.
// scores acc = (64q).(64k) = 4096 q.k -> q.k/16 = acc/65536 too.
#define INV65536 1.52587890625e-05f

typedef _Float16 half8 __attribute__((ext_vector_type(8)));
typedef _Float16 half4 __attribute__((ext_vector_type(4)));
typedef float f32x4 __attribute__((ext_vector_type(4)));

typedef __attribute__((address_space(3))) uint32_t lds_u32;
typedef __attribute__((address_space(1))) uint32_t glb_u32;

// 16B async global->LDS. LDS dest wave-uniform; HW adds lane*16.
__device__ __forceinline__ void gll16(const _Float16* g, _Float16* l) {
  __builtin_amdgcn_global_load_lds((const glb_u32*)g, (lds_u32*)l, 16, 0, 0);
}

__device__ __forceinline__ void split2(float v, _Float16& h, _Float16& l) {
  h = (_Float16)v;
  l = (_Float16)(v - (float)h);
}

// =====================================================================
// prep_w: W[k][n] fp32 -> W_T[n][k] fp16x2, scaled by 1024.
// =====================================================================
__global__ __launch_bounds__(256) void prep_w(const float* __restrict__ wq,
                                              const float* __restrict__ wk,
                                              const float* __restrict__ wv,
                                              const float* __restrict__ w1,
                                              const float* __restrict__ w2,
                                              _Float16* __restrict__ WT) {
  const int idx = blockIdx.x * 256 + threadIdx.x;  // < 5*65536
  const int wsel = idx >> 16;
  const int rem = idx & 65535;
  const int k = rem >> 8, n = rem & 255;
  const float* src = (wsel == 0) ? wq : (wsel == 1) ? wk : (wsel == 2) ? wv : (wsel == 3) ? w1 : w2;
  const float v = src[rem] * 1024.0f;
  _Float16 h1, h2;
  split2(v, h1, h2);
  WT[(size_t)wsel * 131072 + n * 256 + k] = h1;
  WT[(size_t)wsel * 131072 + 65536 + n * 256 + k] = h2;
}

// LDS tile layout: [128 rows][8 chunks of 8 halfs], chunk XOR-swizzled by (row&7)
#define SWZ_OFF(r, cc) ((r) * 64 + (((cc) ^ ((r)&7)) << 3))

// =====================================================================
// gemm_qkv: fused Q/K/V projection. A = x fp32 (split *64 on the fly),
// B = W_T splits (global_load_lds). Q,K -> split(64*val); V -> fp32.
// grid (6, 256): x = wsel*2 + ntile
// =====================================================================
__global__ __launch_bounds__(256) void gemm_qkv(const float* __restrict__ x,
                                                const _Float16* __restrict__ WT,
                                                const float* __restrict__ bq,
                                                const float* __restrict__ bk,
                                                const float* __restrict__ bv,
                                                _Float16* __restrict__ Q1, _Float16* __restrict__ Q2,
                                                _Float16* __restrict__ K1, _Float16* __restrict__ K2,
                                                float* __restrict__ V) {
  __shared__ _Float16 sm[4 * 8192];
  _Float16* sA1 = sm;
  _Float16* sA2 = sm + 8192;
  _Float16* sB1 = sm + 16384;
  _Float16* sB2 = sm + 24576;

  const int tid = threadIdx.x;
  const int lane = tid & 63, w = tid >> 6;
  const int r16 = lane & 15, kg = lane >> 4;
  const int rsub = lane >> 3, csub = lane & 7;
  const int wm = (w >> 1) * 64, wn = (w & 1) * 64;

  const int wsel = blockIdx.x >> 1;
  const int n0 = (blockIdx.x & 1) * 128;
  const int m0 = blockIdx.y * 128;
  const _Float16* B1 = WT + (size_t)wsel * 131072;
  const _Float16* B2 = B1 + 65536;

  const int ra = tid >> 1, hh = tid & 1;

  f32x4 acc[4][4];
#pragma unroll
  for (int i = 0; i < 4; ++i)
#pragma unroll
    for (int j = 0; j < 4; ++j) acc[i][j] = f32x4{0.f, 0.f, 0.f, 0.f};

  for (int k0 = 0; k0 < DD; k0 += 64) {
    const float* xr = x + (size_t)(m0 + ra) * DD + k0 + hh * 32;
    float4 xv[8];
#pragma unroll
    for (int i = 0; i < 8; ++i) xv[i] = *(const float4*)(xr + i * 4);

    __syncthreads();  // previous compute done; LDS free

#pragma unroll
    for (int it = 0; it < 4; ++it) {
      const int r = (w << 5) + (it << 3) + rsub;
      const size_t soff = (size_t)(n0 + r) * DD + k0 + ((csub ^ (r & 7)) << 3);
      gll16(B1 + soff, sB1 + (w << 11) + (it << 9));
      gll16(B2 + soff, sB2 + (w << 11) + (it << 9));
    }
    // A tile: split (64*x) -> fp16x2, swizzled ds_write (rotated chunk order)
#pragma unroll
    for (int qq = 0; qq < 4; ++qq) {
      const int q = (qq + (tid & 3)) & 3;
      const float4 u0 = xv[q * 2], u1 = xv[q * 2 + 1];
      const float vals[8] = {u0.x, u0.y, u0.z, u0.w, u1.x, u1.y, u1.z, u1.w};
      half8 hi, lo;
#pragma unroll
      for (int e = 0; e < 8; ++e) {
        _Float16 a, b;
        split2(vals[e] * 64.0f, a, b);
        hi[e] = a;
        lo[e] = b;
      }
      const int off = SWZ_OFF(ra, hh * 4 + q);
      *(half8*)(sA1 + off) = hi;
      *(half8*)(sA2 + off) = lo;
    }
    __syncthreads();

#pragma unroll
    for (int s = 0; s < 2; ++s) {
      half8 aA[4], aB[4], bA[4], bB[4];
#pragma unroll
      for (int mi = 0; mi < 4; ++mi) {
        const int off = SWZ_OFF(wm + mi * 16 + r16, s * 4 + kg);
        aA[mi] = *(const half8*)(sA1 + off);
        aB[mi] = *(const half8*)(sA2 + off);
      }
#pragma unroll
      for (int nj = 0; nj < 4; ++nj) {
        const int off = SWZ_OFF(wn + nj * 16 + r16, s * 4 + kg);
        bA[nj] = *(const half8*)(sB1 + off);
        bB[nj] = *(const half8*)(sB2 + off);
      }
#pragma unroll
      for (int mi = 0; mi < 4; ++mi)
#pragma unroll
        for (int nj = 0; nj < 4; ++nj) {
          acc[mi][nj] = __builtin_amdgcn_mfma_f32_16x16x32_f16(aA[mi], bA[nj], acc[mi][nj], 0, 0, 0);
          acc[mi][nj] = __builtin_amdgcn_mfma_f32_16x16x32_f16(aA[mi], bB[nj], acc[mi][nj], 0, 0, 0);
          acc[mi][nj] = __builtin_amdgcn_mfma_f32_16x16x32_f16(aB[mi], bA[nj], acc[mi][nj], 0, 0, 0);
        }
    }
  }

  const float* bsel = (wsel == 0) ? bq : (wsel == 1) ? bk : bv;
  _Float16* P1 = (wsel == 0) ? Q1 : K1;
  _Float16* P2 = (wsel == 0) ? Q2 : K2;
#pragma unroll
  for (int mi = 0; mi < 4; ++mi)
#pragma unroll
    for (int nj = 0; nj < 4; ++nj) {
      const int col = n0 + wn + nj * 16 + r16;
#pragma unroll
      for (int j = 0; j < 4; ++j) {
        const int rr = m0 + wm + mi * 16 + kg * 4 + j;
        if (wsel == 2) {
          V[(size_t)rr * DD + col] = acc[mi][nj][j] * INV65536 + bsel[col];
        } else {
          // store 64*Q = acc/1024 + 64*bias
          const float qv = acc[mi][nj][j] * (1.0f / 1024.0f) + 64.0f * bsel[col];
          _Float16 h1, h2;
          split2(qv, h1, h2);
          P1[(size_t)rr * DD + col] = h1;
          P2[(size_t)rr * DD + col] = h2;
        }
      }
    }
}

// =====================================================================
// gemm_split<EPI>: A,B pre-split fp16x2, K-major rows (NT).
// EPI 0: C = acc/65536 + bias          (w1 -> H fp32)
// EPI 1: C = acc/65536 + bias + resid  (w2 -> out fp32)
// EPI 2: S = acc/65536 + adj           (scores)
// =====================================================================
template <int EPI>
__global__ __launch_bounds__(256) void gemm_split(const _Float16* __restrict__ A1,
                                                  const _Float16* __restrict__ A2,
                                                  const _Float16* __restrict__ B1g,
                                                  const _Float16* __restrict__ B2g,
                                                  const float* __restrict__ bias,
                                                  const float* __restrict__ resid,
                                                  float* __restrict__ C) {
  __shared__ _Float16 sm[4 * 8192];
  _Float16* sA1 = sm;
  _Float16* sA2 = sm + 8192;
  _Float16* sB1 = sm + 16384;
  _Float16* sB2 = sm + 24576;

  const int tid = threadIdx.x;
  const int lane = tid & 63, w = tid >> 6;
  const int r16 = lane & 15, kg = lane >> 4;
  const int rsub = lane >> 3, csub = lane & 7;
  const int wm = (w >> 1) * 64, wn = (w & 1) * 64;

  const int n0 = blockIdx.x * 128;
  const int m0 = blockIdx.y * 128;

  const _Float16* pB1 = B1g;
  const _Float16* pB2 = B2g;
  if (EPI == 2) {
    const size_t boff = (size_t)(m0 >> 10) * NNODES * DD;
    pB1 += boff;
    pB2 += boff;
  }

  f32x4 acc[4][4];
#pragma unroll
  for (int i = 0; i < 4; ++i)
#pragma unroll
    for (int j = 0; j < 4; ++j) acc[i][j] = f32x4{0.f, 0.f, 0.f, 0.f};

  for (int k0 = 0; k0 < DD; k0 += 64) {
    __syncthreads();
#pragma unroll
    for (int it = 0; it < 4; ++it) {
      const int r = (w << 5) + (it << 3) + rsub;
      const int swz = ((csub ^ (r & 7)) << 3);
      const int ldso = (w << 11) + (it << 9);
      gll16(A1 + (size_t)(m0 + r) * DD + k0 + swz, sA1 + ldso);
      gll16(A2 + (size_t)(m0 + r) * DD + k0 + swz, sA2 + ldso);
      gll16(pB1 + (size_t)(n0 + r) * DD + k0 + swz, sB1 + ldso);
      gll16(pB2 + (size_t)(n0 + r) * DD + k0 + swz, sB2 + ldso);
    }
    __syncthreads();

#pragma unroll
    for (int s = 0; s < 2; ++s) {
      half8 aA[4], aB[4], bA[4], bB[4];
#pragma unroll
      for (int mi = 0; mi < 4; ++mi) {
        const int off = SWZ_OFF(wm + mi * 16 + r16, s * 4 + kg);
        aA[mi] = *(const half8*)(sA1 + off);
        aB[mi] = *(const half8*)(sA2 + off);
      }
#pragma unroll
      for (int nj = 0; nj < 4; ++nj) {
        const int off = SWZ_OFF(wn + nj * 16 + r16, s * 4 + kg);
        bA[nj] = *(const half8*)(sB1 + off);
        bB[nj] = *(const half8*)(sB2 + off);
      }
#pragma unroll
      for (int mi = 0; mi < 4; ++mi)
#pragma unroll
        for (int nj = 0; nj < 4; ++nj) {
          acc[mi][nj] = __builtin_amdgcn_mfma_f32_16x16x32_f16(aA[mi], bA[nj], acc[mi][nj], 0, 0, 0);
          acc[mi][nj] = __builtin_amdgcn_mfma_f32_16x16x32_f16(aA[mi], bB[nj], acc[mi][nj], 0, 0, 0);
          acc[mi][nj] = __builtin_amdgcn_mfma_f32_16x16x32_f16(aB[mi], bA[nj], acc[mi][nj], 0, 0, 0);
        }
    }
  }

#pragma unroll
  for (int mi = 0; mi < 4; ++mi)
#pragma unroll
    for (int nj = 0; nj < 4; ++nj) {
      const int col = n0 + wn + nj * 16 + r16;
#pragma unroll
      for (int j = 0; j < 4; ++j) {
        const int rr = m0 + wm + mi * 16 + kg * 4 + j;
        const float v = acc[mi][nj][j] * INV65536;
        if (EPI == 2) {
          C[(size_t)rr * NNODES + col] = v + bias[(size_t)(rr & (NNODES - 1)) * NNODES + col];
        } else if (EPI == 0) {
          C[(size_t)rr * DD + col] = v + bias[col];
        } else {
          C[(size_t)rr * DD + col] = v + bias[col] + resid[(size_t)rr * DD + col];
        }
      }
    }
}

// =====================================================================
// Top-64 with exact disambiguation + masked softmax (in-place) +
// sparse messages. One wave per row.
// Elements with s > s64+DELTA: provably in. s < s64-DELTA: provably out.
// Candidates in [s64-DELTA, s64+DELTA]: exact fp32 recompute from split
// Q,K; rank by (score desc, index asc) = jax top_k tie semantics.
// =====================================================================
__global__ __launch_bounds__(256) void topk_softmax_msg(float* __restrict__ S,
                                                        const float* __restrict__ V,
                                                        const _Float16* __restrict__ Q1,
                                                        const _Float16* __restrict__ Q2,
                                                        const _Float16* __restrict__ K1,
                                                        const _Float16* __restrict__ K2,
                                                        const float* __restrict__ adj,
                                                        _Float16* __restrict__ M1,
                                                        _Float16* __restrict__ M2) {
  const int tid = threadIdx.x;
  const int w = tid >> 6, lane = tid & 63;
  const int row = blockIdx.x * 4 + w;
  const int b = row >> 10;
  const int m = row & (NNODES - 1);
  float* Srow = S + (size_t)row * NNODES;

  __shared__ int sidx[4][KNB];
  __shared__ float swgt[4][KNB];
  __shared__ int cidxs[4][32];
  __shared__ float cex[4][32];
  __shared__ int csel[4][32];

  float s[16];
  unsigned key[16];
#pragma unroll
  for (int i = 0; i < 16; ++i) {
    float v = Srow[i * 64 + lane];
    s[i] = v;
    unsigned bits = __float_as_uint(v);
    key[i] = (bits & 0x80000000u) ? ~bits : (bits | 0x80000000u);
  }

  // 64th-largest key via MSB-first greedy radix search
  unsigned cur = 0u;
#pragma unroll 1
  for (int bit = 31; bit >= 0; --bit) {
    const unsigned cand = cur | (1u << bit);
    int cnt = 0;
#pragma unroll
    for (int i = 0; i < 16; ++i) cnt += (key[i] >= cand) ? 1 : 0;
#pragma unroll
    for (int off = 32; off > 0; off >>= 1) cnt += __shfl_xor(cnt, off);
    if (cnt >= KNB) cur = cand;
  }

  // decode s64
  const unsigned b64u = (cur & 0x80000000u) ? (cur & 0x7fffffffu) : ~cur;
  const float s64 = __uint_as_float(b64u);
  const float DELTA = 1e-3f;

  // classify: hi / candidate / lo; candidates compacted in index order
  const unsigned long long ltmask = (1ull << lane) - 1ull;
  unsigned himask = 0u, candmask = 0u;
  int cpos[16];
  int nhi = 0, ncand = 0;
#pragma unroll
  for (int i = 0; i < 16; ++i) {
    const bool hi = (s[i] > s64 + DELTA);
    const bool cd = (!hi) && (s[i] >= s64 - DELTA);
    const unsigned long long balh = __ballot(hi);
    const unsigned long long balc = __ballot(cd);
    if (hi) himask |= (1u << i);
    cpos[i] = -1;
    if (cd) {
      candmask |= (1u << i);
      const int p = ncand + (int)__popcll(balc & ltmask);
      cpos[i] = p;
      if (p < 32) cidxs[w][p] = i * 64 + lane;
    }
    nhi += (int)__popcll(balh);
    ncand += (int)__popcll(balc);
  }
  const int need = KNB - nhi;  // >= 1, and ncand >= need

  unsigned selmask;
  if (ncand == need) {
    // fast path: all candidates selected, no recompute
    selmask = himask | candmask;
  } else {
    // slow path: exact fp32 recompute for candidates
    const int nc = (ncand <= 32) ? ncand : 32;
    const int nd = (need <= nc) ? need : nc;
    const size_t qoff = (size_t)row * DD + lane * 4;
    const half4 q1v = *(const half4*)(Q1 + qoff);
    const half4 q2v = *(const half4*)(Q2 + qoff);
    float qf[4];
#pragma unroll
    for (int e = 0; e < 4; ++e) qf[e] = (float)q1v[e] + (float)q2v[e];
    const float* adjrow = adj + (size_t)m * NNODES;
#pragma unroll 1
    for (int t = 0; t < nc; ++t) {
      const int j = cidxs[w][t];
      const size_t koff = ((size_t)b * NNODES + j) * DD + lane * 4;
      const half4 k1v = *(const half4*)(K1 + koff);
      const half4 k2v = *(const half4*)(K2 + koff);
      float part = 0.0f;
#pragma unroll
      for (int e = 0; e < 4; ++e) part = fmaf(qf[e], (float)k1v[e] + (float)k2v[e], part);
#pragma unroll
      for (int off = 32; off > 0; off >>= 1) part += __shfl_xor(part, off);
      if (lane == 0) cex[w][t] = part * INV65536 + adjrow[j];
    }
    if (lane < nc) {
      const float et = cex[w][lane];
      int rank = 0;
      for (int u = 0; u < nc; ++u) {
        const float eu = cex[w][u];
        rank += (eu > et || (eu == et && u < lane)) ? 1 : 0;
      }
      csel[w][lane] = (rank < nd) ? 1 : 0;
    }
    selmask = himask;
#pragma unroll
    for (int i = 0; i < 16; ++i) {
      if (((candmask >> i) & 1u) && cpos[i] < 32 && csel[w][cpos[i]]) selmask |= (1u << i);
    }
  }

  // softmax over selected (row max is always selected)
  float rmax = s[0];
#pragma unroll
  for (int i = 1; i < 16; ++i) rmax = fmaxf(rmax, s[i]);
#pragma unroll
  for (int off = 32; off > 0; off >>= 1) rmax = fmaxf(rmax, __shfl_xor(rmax, off));

  float p[16];
  float sum = 0.0f;
#pragma unroll
  for (int i = 0; i < 16; ++i) {
    p[i] = __expf(s[i] - rmax);
    if ((selmask >> i) & 1u) sum += p[i];
  }
#pragma unroll
  for (int off = 32; off > 0; off >>= 1) sum += __shfl_xor(sum, off);
  const float inv = 1.0f / sum;

  // write attn row + compact selected (index order) into LDS
  int run2 = 0;
#pragma unroll
  for (int i = 0; i < 16; ++i) {
    const bool sel = (selmask >> i) & 1u;
    const unsigned long long bal = __ballot(sel);
    const float aw = sel ? p[i] * inv : 0.0f;
    Srow[i * 64 + lane] = aw;
    if (sel) {
      const int pos = run2 + (int)__popcll(bal & ltmask);
      sidx[w][pos] = i * 64 + lane;
      swgt[w][pos] = aw;
    }
    run2 += (int)__popcll(bal);
  }

  // messages: lane owns output dims [lane*4, lane*4+4)
  const float* Vb = V + (size_t)b * NNODES * DD;
  float4 acc = {0.0f, 0.0f, 0.0f, 0.0f};
  for (int t = 0; t < KNB; ++t) {
    const int j = sidx[w][t];
    const float wg = swgt[w][t];
    const float4 vv = *(const float4*)(Vb + (size_t)j * DD + lane * 4);
    acc.x = fmaf(wg, vv.x, acc.x);
    acc.y = fmaf(wg, vv.y, acc.y);
    acc.z = fmaf(wg, vv.z, acc.z);
    acc.w = fmaf(wg, vv.w, acc.w);
  }
  const float av[4] = {acc.x, acc.y, acc.z, acc.w};
  half4 m1, m2;
#pragma unroll
  for (int d = 0; d < 4; ++d) {
    _Float16 a, bb;
    split2(av[d] * 64.0f, a, bb);
    m1[d] = a;
    m2[d] = bb;
  }
  *(half4*)(M1 + (size_t)row * DD + lane * 4) = m1;
  *(half4*)(M2 + (size_t)row * DD + lane * 4) = m2;
}

// =====================================================================
// LayerNorm + ReLU: H fp32 -> split(64*y).
// =====================================================================
__global__ __launch_bounds__(256) void ln_relu(const float* __restrict__ H,
                                               const float* __restrict__ g,
                                               const float* __restrict__ bta,
                                               _Float16* __restrict__ H1,
                                               _Float16* __restrict__ H2) {
  const int row = blockIdx.x;
  const int c = threadIdx.x;
  const int wv = c >> 6, ln = c & 63;
  const float h = H[(size_t)row * DD + c];

  __shared__ float part[4], part2[4];
  float v = h;
#pragma unroll
  for (int off = 32; off > 0; off >>= 1) v += __shfl_xor(v, off);
  if (ln == 0) part[wv] = v;
  __syncthreads();
  const float mu = (part[0] + part[1] + part[2] + part[3]) * (1.0f / 256.0f);

  const float d = h - mu;
  float sq = d * d;
#pragma unroll
  for (int off = 32; off > 0; off >>= 1) sq += __shfl_xor(sq, off);
  if (ln == 0) part2[wv] = sq;
  __syncthreads();
  const float var = (part2[0] + part2[1] + part2[2] + part2[3]) * (1.0f / 256.0f);

  const float y = fmaxf(d * (1.0f / sqrtf(var + 1e-5f)) * g[c] + bta[c], 0.0f);
  _Float16 h1, h2;
  split2(y * 64.0f, h1, h2);
  H1[(size_t)row * DD + c] = h1;
  H2[(size_t)row * DD + c] = h2;
}

// =====================================================================
// Host launch
// =====================================================================
extern "C" void kernel_launch(void* const* d_in, const int* in_sizes, int n_in,
                              void* d_out, int out_size, void* d_ws, size_t ws_size,
                              hipStream_t stream) {
  (void)in_sizes; (void)n_in; (void)out_size; (void)ws_size;
  const float* x   = (const float*)d_in[0];
  const float* wq  = (const float*)d_in[1];
  const float* bq  = (const float*)d_in[2];
  const float* wk  = (const float*)d_in[3];
  const float* bk  = (const float*)d_in[4];
  const float* wv  = (const float*)d_in[5];
  const float* bv  = (const float*)d_in[6];
  const float* adj = (const float*)d_in[7];
  const float* w1  = (const float*)d_in[8];
  const float* b1  = (const float*)d_in[9];
  const float* lng = (const float*)d_in[10];
  const float* lnb = (const float*)d_in[11];
  const float* w2  = (const float*)d_in[12];
  const float* b2  = (const float*)d_in[13];

  const size_t BND = (size_t)MTOT * DD;  // 8,388,608
  float* outp  = (float*)d_out;          // [MTOT][256] (holds V until w2 overwrites)
  float* attnp = outp + BND;             // [MTOT][1024] (S, then attn)
  float* V = outp;

  _Float16* Q1 = (_Float16*)d_ws;  // 68.4 MB total ws use
  _Float16* Q2 = Q1 + BND;
  _Float16* K1 = Q2 + BND;
  _Float16* K2 = K1 + BND;
  _Float16* WT = K2 + BND;  // [5][2][65536]
  _Float16* M1 = Q1;        // reuse after scores (Q needed through topk: see below)
  _Float16* M2 = Q2;
  float* H = (float*)K1;    // reuse K region after topk
  _Float16* H1 = Q1;
  _Float16* H2 = Q2;

  const dim3 blk(256);

  prep_w<<<dim3(1280), blk, 0, stream>>>(wq, wk, wv, w1, w2, WT);
  gemm_qkv<<<dim3(6, 256), blk, 0, stream>>>(x, WT, bq, bk, bv, Q1, Q2, K1, K2, V);
  gemm_split<2><<<dim3(8, 256), blk, 0, stream>>>(Q1, Q2, K1, K2, adj, nullptr, attnp);
  // NOTE: topk reads Q1/Q2/K1/K2 (disambiguation) and writes M1/M2 = Q1/Q2.
  // Safe: M row `row` is written only after the wave finished all Q-reads of
  // row `row`; Q reads are only of the wave's OWN row (qoff) -- each wave
  // reads Q[row] before writing M[row], and no other wave touches that row.
  topk_softmax_msg<<<dim3(MTOT / 4), blk, 0, stream>>>(attnp, V, Q1, Q2, K1, K2, adj, M1, M2);
  gemm_split<0><<<dim3(2, 256), blk, 0, stream>>>(M1, M2, WT + 3 * 131072, WT + 3 * 131072 + 65536,
                                                  b1, nullptr, H);
  ln_relu<<<dim3(MTOT), blk, 0, stream>>>(H, lng, lnb, H1, H2);
  gemm_split<1><<<dim3(2, 256), blk, 0, stream>>>(H1, H2, WT + 4 * 131072, WT + 4 * 131072 + 65536,
                                                  b2, V, outp);
}

// Round 4
// 462.788 us; speedup vs baseline: 1.4341x; 1.1371x over previous
//
#include <hip/hip_runtime.h>
#include <cstdint>

#define NB 32
#define NNODES 1024
#define DD 256
#define KNB 64
#define MTOT (NB * NNODES)  // 32768

// Scaling: activations stored as split(64*a), weights as split(1024*w).
// acc = sum (64a)(1024w) = 65536 * a.w  -> epilogue * 1/65536.
// scores acc = (64q).(64k) = 4096 q.k -> q.k/16 = acc/65536 too.
#define INV65536 1.52587890625e-05f

typedef _Float16 half8 __attribute__((ext_vector_type(8)));
typedef _Float16 half4 __attribute__((ext_vector_type(4)));
typedef float f32x4 __attribute__((ext_vector_type(4)));

typedef __attribute__((address_space(3))) uint32_t lds_u32;
typedef __attribute__((address_space(1))) uint32_t glb_u32;

// 16B async global->LDS. LDS dest wave-uniform; HW adds lane*16.
__device__ __forceinline__ void gll16(const _Float16* g, _Float16* l) {
  __builtin_amdgcn_global_load_lds((const glb_u32*)g, (lds_u32*)l, 16, 0, 0);
}

__device__ __forceinline__ void split2(float v, _Float16& h, _Float16& l) {
  h = (_Float16)v;
  l = (_Float16)(v - (float)h);
}

// =====================================================================
// prep_w: W[k][n] fp32 -> W_T[n][k] fp16x2, scaled by 1024.
// =====================================================================
__global__ __launch_bounds__(256) void prep_w(const float* __restrict__ wq,
                                              const float* __restrict__ wk,
                                              const float* __restrict__ wv,
                                              const float* __restrict__ w1,
                                              const float* __restrict__ w2,
                                              _Float16* __restrict__ WT) {
  const int idx = blockIdx.x * 256 + threadIdx.x;  // < 5*65536
  const int wsel = idx >> 16;
  const int rem = idx & 65535;
  const int k = rem >> 8, n = rem & 255;
  const float* src = (wsel == 0) ? wq : (wsel == 1) ? wk : (wsel == 2) ? wv : (wsel == 3) ? w1 : w2;
  const float v = src[rem] * 1024.0f;
  _Float16 h1, h2;
  split2(v, h1, h2);
  WT[(size_t)wsel * 131072 + n * 256 + k] = h1;
  WT[(size_t)wsel * 131072 + 65536 + n * 256 + k] = h2;
}

// LDS tile layout: [128 rows][8 chunks of 8 halfs], chunk XOR-swizzled by (row&7)
#define SWZ_OFF(r, cc) ((r) * 64 + (((cc) ^ ((r)&7)) << 3))

// =====================================================================
// gemm_qkv: fused Q/K/V projection. A = x fp32 (split *64 on the fly),
// B = W_T splits (global_load_lds). Q,K -> split(64*val); V -> fp32.
// grid (6, 256): x = wsel*2 + ntile
// =====================================================================
__global__ __launch_bounds__(256) void gemm_qkv(const float* __restrict__ x,
                                                const _Float16* __restrict__ WT,
                                                const float* __restrict__ bq,
                                                const float* __restrict__ bk,
                                                const float* __restrict__ bv,
                                                _Float16* __restrict__ Q1, _Float16* __restrict__ Q2,
                                                _Float16* __restrict__ K1, _Float16* __restrict__ K2,
                                                float* __restrict__ V) {
  __shared__ _Float16 sm[4 * 8192];
  _Float16* sA1 = sm;
  _Float16* sA2 = sm + 8192;
  _Float16* sB1 = sm + 16384;
  _Float16* sB2 = sm + 24576;

  const int tid = threadIdx.x;
  const int lane = tid & 63, w = tid >> 6;
  const int r16 = lane & 15, kg = lane >> 4;
  const int rsub = lane >> 3, csub = lane & 7;
  const int wm = (w >> 1) * 64, wn = (w & 1) * 64;

  const int wsel = blockIdx.x >> 1;
  const int n0 = (blockIdx.x & 1) * 128;
  const int m0 = blockIdx.y * 128;
  const _Float16* B1 = WT + (size_t)wsel * 131072;
  const _Float16* B2 = B1 + 65536;

  const int ra = tid >> 1, hh = tid & 1;

  f32x4 acc[4][4];
#pragma unroll
  for (int i = 0; i < 4; ++i)
#pragma unroll
    for (int j = 0; j < 4; ++j) acc[i][j] = f32x4{0.f, 0.f, 0.f, 0.f};

  for (int k0 = 0; k0 < DD; k0 += 64) {
    const float* xr = x + (size_t)(m0 + ra) * DD + k0 + hh * 32;
    float4 xv[8];
#pragma unroll
    for (int i = 0; i < 8; ++i) xv[i] = *(const float4*)(xr + i * 4);

    __syncthreads();  // previous compute done; LDS free

#pragma unroll
    for (int it = 0; it < 4; ++it) {
      const int r = (w << 5) + (it << 3) + rsub;
      const size_t soff = (size_t)(n0 + r) * DD + k0 + ((csub ^ (r & 7)) << 3);
      gll16(B1 + soff, sB1 + (w << 11) + (it << 9));
      gll16(B2 + soff, sB2 + (w << 11) + (it << 9));
    }
    // A tile: split (64*x) -> fp16x2, swizzled ds_write (rotated chunk order)
#pragma unroll
    for (int qq = 0; qq < 4; ++qq) {
      const int q = (qq + (tid & 3)) & 3;
      const float4 u0 = xv[q * 2], u1 = xv[q * 2 + 1];
      const float vals[8] = {u0.x, u0.y, u0.z, u0.w, u1.x, u1.y, u1.z, u1.w};
      half8 hi, lo;
#pragma unroll
      for (int e = 0; e < 8; ++e) {
        _Float16 a, b;
        split2(vals[e] * 64.0f, a, b);
        hi[e] = a;
        lo[e] = b;
      }
      const int off = SWZ_OFF(ra, hh * 4 + q);
      *(half8*)(sA1 + off) = hi;
      *(half8*)(sA2 + off) = lo;
    }
    __syncthreads();

#pragma unroll
    for (int s = 0; s < 2; ++s) {
      half8 aA[4], aB[4], bA[4], bB[4];
#pragma unroll
      for (int mi = 0; mi < 4; ++mi) {
        const int off = SWZ_OFF(wm + mi * 16 + r16, s * 4 + kg);
        aA[mi] = *(const half8*)(sA1 + off);
        aB[mi] = *(const half8*)(sA2 + off);
      }
#pragma unroll
      for (int nj = 0; nj < 4; ++nj) {
        const int off = SWZ_OFF(wn + nj * 16 + r16, s * 4 + kg);
        bA[nj] = *(const half8*)(sB1 + off);
        bB[nj] = *(const half8*)(sB2 + off);
      }
#pragma unroll
      for (int mi = 0; mi < 4; ++mi)
#pragma unroll
        for (int nj = 0; nj < 4; ++nj) {
          acc[mi][nj] = __builtin_amdgcn_mfma_f32_16x16x32_f16(aA[mi], bA[nj], acc[mi][nj], 0, 0, 0);
          acc[mi][nj] = __builtin_amdgcn_mfma_f32_16x16x32_f16(aA[mi], bB[nj], acc[mi][nj], 0, 0, 0);
          acc[mi][nj] = __builtin_amdgcn_mfma_f32_16x16x32_f16(aB[mi], bA[nj], acc[mi][nj], 0, 0, 0);
        }
    }
  }

  const float* bsel = (wsel == 0) ? bq : (wsel == 1) ? bk : bv;
  _Float16* P1 = (wsel == 0) ? Q1 : K1;
  _Float16* P2 = (wsel == 0) ? Q2 : K2;
#pragma unroll
  for (int mi = 0; mi < 4; ++mi)
#pragma unroll
    for (int nj = 0; nj < 4; ++nj) {
      const int col = n0 + wn + nj * 16 + r16;
#pragma unroll
      for (int j = 0; j < 4; ++j) {
        const int rr = m0 + wm + mi * 16 + kg * 4 + j;
        if (wsel == 2) {
          V[(size_t)rr * DD + col] = acc[mi][nj][j] * INV65536 + bsel[col];
        } else {
          // store 64*Q = acc/1024 + 64*bias
          const float qv = acc[mi][nj][j] * (1.0f / 1024.0f) + 64.0f * bsel[col];
          _Float16 h1, h2;
          split2(qv, h1, h2);
          P1[(size_t)rr * DD + col] = h1;
          P2[(size_t)rr * DD + col] = h2;
        }
      }
    }
}

// =====================================================================
// gemm_split<EPI>: A,B pre-split fp16x2, K-major rows (NT).
// EPI 0: C = acc/65536 + bias          (w1 -> H fp32)
// EPI 1: C = acc/65536 + bias + resid  (w2 -> out fp32)
// EPI 2: S = acc/65536 + adj           (scores)
// =====================================================================
template <int EPI>
__global__ __launch_bounds__(256) void gemm_split(const _Float16* __restrict__ A1,
                                                  const _Float16* __restrict__ A2,
                                                  const _Float16* __restrict__ B1g,
                                                  const _Float16* __restrict__ B2g,
                                                  const float* __restrict__ bias,
                                                  const float* __restrict__ resid,
                                                  float* __restrict__ C) {
  __shared__ _Float16 sm[4 * 8192];
  _Float16* sA1 = sm;
  _Float16* sA2 = sm + 8192;
  _Float16* sB1 = sm + 16384;
  _Float16* sB2 = sm + 24576;

  const int tid = threadIdx.x;
  const int lane = tid & 63, w = tid >> 6;
  const int r16 = lane & 15, kg = lane >> 4;
  const int rsub = lane >> 3, csub = lane & 7;
  const int wm = (w >> 1) * 64, wn = (w & 1) * 64;

  const int n0 = blockIdx.x * 128;
  const int m0 = blockIdx.y * 128;

  const _Float16* pB1 = B1g;
  const _Float16* pB2 = B2g;
  if (EPI == 2) {
    const size_t boff = (size_t)(m0 >> 10) * NNODES * DD;
    pB1 += boff;
    pB2 += boff;
  }

  f32x4 acc[4][4];
#pragma unroll
  for (int i = 0; i < 4; ++i)
#pragma unroll
    for (int j = 0; j < 4; ++j) acc[i][j] = f32x4{0.f, 0.f, 0.f, 0.f};

  for (int k0 = 0; k0 < DD; k0 += 64) {
    __syncthreads();
#pragma unroll
    for (int it = 0; it < 4; ++it) {
      const int r = (w << 5) + (it << 3) + rsub;
      const int swz = ((csub ^ (r & 7)) << 3);
      const int ldso = (w << 11) + (it << 9);
      gll16(A1 + (size_t)(m0 + r) * DD + k0 + swz, sA1 + ldso);
      gll16(A2 + (size_t)(m0 + r) * DD + k0 + swz, sA2 + ldso);
      gll16(pB1 + (size_t)(n0 + r) * DD + k0 + swz, sB1 + ldso);
      gll16(pB2 + (size_t)(n0 + r) * DD + k0 + swz, sB2 + ldso);
    }
    __syncthreads();

#pragma unroll
    for (int s = 0; s < 2; ++s) {
      half8 aA[4], aB[4], bA[4], bB[4];
#pragma unroll
      for (int mi = 0; mi < 4; ++mi) {
        const int off = SWZ_OFF(wm + mi * 16 + r16, s * 4 + kg);
        aA[mi] = *(const half8*)(sA1 + off);
        aB[mi] = *(const half8*)(sA2 + off);
      }
#pragma unroll
      for (int nj = 0; nj < 4; ++nj) {
        const int off = SWZ_OFF(wn + nj * 16 + r16, s * 4 + kg);
        bA[nj] = *(const half8*)(sB1 + off);
        bB[nj] = *(const half8*)(sB2 + off);
      }
#pragma unroll
      for (int mi = 0; mi < 4; ++mi)
#pragma unroll
        for (int nj = 0; nj < 4; ++nj) {
          acc[mi][nj] = __builtin_amdgcn_mfma_f32_16x16x32_f16(aA[mi], bA[nj], acc[mi][nj], 0, 0, 0);
          acc[mi][nj] = __builtin_amdgcn_mfma_f32_16x16x32_f16(aA[mi], bB[nj], acc[mi][nj], 0, 0, 0);
          acc[mi][nj] = __builtin_amdgcn_mfma_f32_16x16x32_f16(aB[mi], bA[nj], acc[mi][nj], 0, 0, 0);
        }
    }
  }

#pragma unroll
  for (int mi = 0; mi < 4; ++mi)
#pragma unroll
    for (int nj = 0; nj < 4; ++nj) {
      const int col = n0 + wn + nj * 16 + r16;
#pragma unroll
      for (int j = 0; j < 4; ++j) {
        const int rr = m0 + wm + mi * 16 + kg * 4 + j;
        const float v = acc[mi][nj][j] * INV65536;
        if (EPI == 2) {
          C[(size_t)rr * NNODES + col] = v + bias[(size_t)(rr & (NNODES - 1)) * NNODES + col];
        } else if (EPI == 0) {
          C[(size_t)rr * DD + col] = v + bias[col];
        } else {
          C[(size_t)rr * DD + col] = v + bias[col] + resid[(size_t)rr * DD + col];
        }
      }
    }
}

// =====================================================================
// Top-64 + masked softmax (in-place) + sparse messages. One wave/row.
// v4: 21-bit fixed-point radix (cells of 7.63e-6 over [-8,8)) counted
// via ballot+popcount (scalar pipe), float4 row I/O, packed gather.
// hi (s > cell_lo + 6e-5): provably in top-64.
// lo (s < cell_lo - 5e-5): provably out. (score err eps ~3e-6 << margins)
// candidates between: exact fp32 recompute from split Q,K; rank by
// (score desc, index asc) = jax top_k tie semantics.
// Element order: elem = c*256 + lane*4 + e  ((c,lane,e) lex = ascending).
// =====================================================================
__global__ __launch_bounds__(256) void topk_softmax_msg(float* __restrict__ S,
                                                        const float* __restrict__ V,
                                                        const _Float16* __restrict__ Q1,
                                                        const _Float16* __restrict__ Q2,
                                                        const _Float16* __restrict__ K1,
                                                        const _Float16* __restrict__ K2,
                                                        const float* __restrict__ adj,
                                                        _Float16* __restrict__ M1,
                                                        _Float16* __restrict__ M2) {
  const int tid = threadIdx.x;
  const int w = tid >> 6, lane = tid & 63;
  const int row = blockIdx.x * 4 + w;
  const int b = row >> 10;
  const int m = row & (NNODES - 1);
  float* Srow = S + (size_t)row * NNODES;

  __shared__ float2 spair[4][KNB];  // (wgt, idx bits)
  __shared__ int cidxs[4][32];
  __shared__ float cex[4][32];
  __shared__ int csel[4][32];

  // defensive init (only matters in astronomically-unlikely overflow path)
  if (lane < KNB) spair[w][lane] = make_float2(0.0f, __int_as_float(0));

  // load S row as float4
  float s[16];
#pragma unroll
  for (int c = 0; c < 4; ++c) {
    const float4 sv = *(const float4*)(Srow + c * 256 + lane * 4);
    s[c * 4 + 0] = sv.x;
    s[c * 4 + 1] = sv.y;
    s[c * 4 + 2] = sv.z;
    s[c * 4 + 3] = sv.w;
  }

  // 21-bit fixed-point keys (monotone; truncation)
  unsigned key[16];
#pragma unroll
  for (int t = 0; t < 16; ++t) {
    const float f = fminf(fmaxf((s[t] + 8.0f) * 131072.0f, 0.0f), 2097151.0f);
    key[t] = (unsigned)f;
  }

  // radix-select 64th-largest key; per-bit count on scalar pipe
  unsigned cur = 0u;
#pragma unroll 1
  for (int bit = 20; bit >= 0; --bit) {
    const unsigned cand = cur | (1u << bit);
    int cnt = 0;
#pragma unroll
    for (int t = 0; t < 16; ++t) cnt += (int)__popcll(__ballot(key[t] >= cand));
    if (cnt >= KNB) cur = cand;
  }

  // float-domain classification around the 64th key's cell
  const float s64f = (float)cur * (16.0f / 2097152.0f) - 8.0f;  // cell lower edge
  const float thrHi = s64f + 6e-5f;
  const float thrLo = s64f - 5e-5f;

  const unsigned long long ltmask = (1ull << lane) - 1ull;
  unsigned hm = 0u, cm = 0u;
  int cpos[16];
  int nhi = 0, ncand = 0;
#pragma unroll
  for (int c = 0; c < 4; ++c) {
    bool hiv[4], cdv[4];
    unsigned long long mh[4], mc[4];
#pragma unroll
    for (int e = 0; e < 4; ++e) {
      const int t = c * 4 + e;
      hiv[e] = (s[t] > thrHi);
      cdv[e] = (!hiv[e]) && (s[t] >= thrLo);
      mh[e] = __ballot(hiv[e]);
      mc[e] = __ballot(cdv[e]);
    }
    const int below = (int)__popcll(mc[0] & ltmask) + (int)__popcll(mc[1] & ltmask) +
                      (int)__popcll(mc[2] & ltmask) + (int)__popcll(mc[3] & ltmask);
    int own = 0;
#pragma unroll
    for (int e = 0; e < 4; ++e) {
      const int t = c * 4 + e;
      cpos[t] = -1;
      if (hiv[e]) hm |= (1u << t);
      if (cdv[e]) {
        cm |= (1u << t);
        const int p = ncand + below + own;
        cpos[t] = p;
        if (p < 32) cidxs[w][p] = c * 256 + lane * 4 + e;
        ++own;
      }
    }
    nhi += (int)__popcll(mh[0]) + (int)__popcll(mh[1]) + (int)__popcll(mh[2]) + (int)__popcll(mh[3]);
    ncand += (int)__popcll(mc[0]) + (int)__popcll(mc[1]) + (int)__popcll(mc[2]) + (int)__popcll(mc[3]);
  }
  const int need = KNB - nhi;  // >= 1; ncand >= need

  unsigned selm;
  if (ncand == need) {
    selm = hm | cm;  // fast path (most rows)
  } else {
    const int nc = (ncand <= 32) ? ncand : 32;
    const int nd = (need <= nc) ? need : nc;
    const size_t qoff = (size_t)row * DD + lane * 4;
    const half4 q1v = *(const half4*)(Q1 + qoff);
    const half4 q2v = *(const half4*)(Q2 + qoff);
    float qf[4];
#pragma unroll
    for (int e = 0; e < 4; ++e) qf[e] = (float)q1v[e] + (float)q2v[e];
    const float* adjrow = adj + (size_t)m * NNODES;
#pragma unroll 1
    for (int t2 = 0; t2 < nc; ++t2) {
      const int j = cidxs[w][t2];
      const size_t koff = ((size_t)b * NNODES + j) * DD + lane * 4;
      const half4 k1v = *(const half4*)(K1 + koff);
      const half4 k2v = *(const half4*)(K2 + koff);
      float part = 0.0f;
#pragma unroll
      for (int e = 0; e < 4; ++e) part = fmaf(qf[e], (float)k1v[e] + (float)k2v[e], part);
#pragma unroll
      for (int off = 32; off > 0; off >>= 1) part += __shfl_xor(part, off);
      if (lane == 0) cex[w][t2] = part * INV65536 + adjrow[j];
    }
    if (lane < nc) {
      const float et = cex[w][lane];
      int rank = 0;
      for (int u = 0; u < nc; ++u) {
        const float eu = cex[w][u];
        rank += (eu > et || (eu == et && u < lane)) ? 1 : 0;
      }
      csel[w][lane] = (rank < nd) ? 1 : 0;
    }
    selm = hm;
#pragma unroll
    for (int t = 0; t < 16; ++t) {
      if (((cm >> t) & 1u) && cpos[t] >= 0 && cpos[t] < 32 && csel[w][cpos[t]]) selm |= (1u << t);
    }
  }

  // softmax over selected (rmax over all; top element is hi|cand, exp<=1 safe)
  float rmax = s[0];
#pragma unroll
  for (int t = 1; t < 16; ++t) rmax = fmaxf(rmax, s[t]);
#pragma unroll
  for (int off = 32; off > 0; off >>= 1) rmax = fmaxf(rmax, __shfl_xor(rmax, off));

  float p[16];
  float sum = 0.0f;
#pragma unroll
  for (int t = 0; t < 16; ++t) {
    p[t] = __expf(s[t] - rmax);
    if ((selm >> t) & 1u) sum += p[t];
  }
#pragma unroll
  for (int off = 32; off > 0; off >>= 1) sum += __shfl_xor(sum, off);
  const float inv = 1.0f / sum;

  // attn write (float4) + compact selected (index order) into spair
  int run = 0;
#pragma unroll
  for (int c = 0; c < 4; ++c) {
    bool sel4[4];
    unsigned long long ms[4];
#pragma unroll
    for (int e = 0; e < 4; ++e) {
      sel4[e] = (selm >> (c * 4 + e)) & 1u;
      ms[e] = __ballot(sel4[e]);
    }
    const int below = (int)__popcll(ms[0] & ltmask) + (int)__popcll(ms[1] & ltmask) +
                      (int)__popcll(ms[2] & ltmask) + (int)__popcll(ms[3] & ltmask);
    float4 ow;
    float* owp = (float*)&ow;
    int own = 0;
#pragma unroll
    for (int e = 0; e < 4; ++e) {
      const int t = c * 4 + e;
      const float aw = sel4[e] ? p[t] * inv : 0.0f;
      owp[e] = aw;
      if (sel4[e]) {
        const int pos = run + below + own;
        if (pos < KNB) spair[w][pos] = make_float2(aw, __int_as_float(c * 256 + lane * 4 + e));
        ++own;
      }
    }
    *(float4*)(Srow + c * 256 + lane * 4) = ow;
    run += (int)__popcll(ms[0]) + (int)__popcll(ms[1]) + (int)__popcll(ms[2]) + (int)__popcll(ms[3]);
  }

  // messages: lane owns output dims [lane*4, lane*4+4)
  const float* Vb = V + (size_t)b * NNODES * DD;
  float4 acc = {0.0f, 0.0f, 0.0f, 0.0f};
#pragma unroll 2
  for (int t = 0; t < KNB; ++t) {
    const float2 pr = spair[w][t];
    const int j = __float_as_int(pr.y);
    const float4 vv = *(const float4*)(Vb + (size_t)j * DD + lane * 4);
    acc.x = fmaf(pr.x, vv.x, acc.x);
    acc.y = fmaf(pr.x, vv.y, acc.y);
    acc.z = fmaf(pr.x, vv.z, acc.z);
    acc.w = fmaf(pr.x, vv.w, acc.w);
  }
  const float av[4] = {acc.x, acc.y, acc.z, acc.w};
  half4 m1, m2;
#pragma unroll
  for (int d = 0; d < 4; ++d) {
    _Float16 a, bb;
    split2(av[d] * 64.0f, a, bb);
    m1[d] = a;
    m2[d] = bb;
  }
  *(half4*)(M1 + (size_t)row * DD + lane * 4) = m1;
  *(half4*)(M2 + (size_t)row * DD + lane * 4) = m2;
}

// =====================================================================
// LayerNorm + ReLU: H fp32 -> split(64*y).
// =====================================================================
__global__ __launch_bounds__(256) void ln_relu(const float* __restrict__ H,
                                               const float* __restrict__ g,
                                               const float* __restrict__ bta,
                                               _Float16* __restrict__ H1,
                                               _Float16* __restrict__ H2) {
  const int row = blockIdx.x;
  const int c = threadIdx.x;
  const int wv = c >> 6, ln = c & 63;
  const float h = H[(size_t)row * DD + c];

  __shared__ float part[4], part2[4];
  float v = h;
#pragma unroll
  for (int off = 32; off > 0; off >>= 1) v += __shfl_xor(v, off);
  if (ln == 0) part[wv] = v;
  __syncthreads();
  const float mu = (part[0] + part[1] + part[2] + part[3]) * (1.0f / 256.0f);

  const float d = h - mu;
  float sq = d * d;
#pragma unroll
  for (int off = 32; off > 0; off >>= 1) sq += __shfl_xor(sq, off);
  if (ln == 0) part2[wv] = sq;
  __syncthreads();
  const float var = (part2[0] + part2[1] + part2[2] + part2[3]) * (1.0f / 256.0f);

  const float y = fmaxf(d * (1.0f / sqrtf(var + 1e-5f)) * g[c] + bta[c], 0.0f);
  _Float16 h1, h2;
  split2(y * 64.0f, h1, h2);
  H1[(size_t)row * DD + c] = h1;
  H2[(size_t)row * DD + c] = h2;
}

// =====================================================================
// Host launch
// =====================================================================
extern "C" void kernel_launch(void* const* d_in, const int* in_sizes, int n_in,
                              void* d_out, int out_size, void* d_ws, size_t ws_size,
                              hipStream_t stream) {
  (void)in_sizes; (void)n_in; (void)out_size; (void)ws_size;
  const float* x   = (const float*)d_in[0];
  const float* wq  = (const float*)d_in[1];
  const float* bq  = (const float*)d_in[2];
  const float* wk  = (const float*)d_in[3];
  const float* bk  = (const float*)d_in[4];
  const float* wv  = (const float*)d_in[5];
  const float* bv  = (const float*)d_in[6];
  const float* adj = (const float*)d_in[7];
  const float* w1  = (const float*)d_in[8];
  const float* b1  = (const float*)d_in[9];
  const float* lng = (const float*)d_in[10];
  const float* lnb = (const float*)d_in[11];
  const float* w2  = (const float*)d_in[12];
  const float* b2  = (const float*)d_in[13];

  const size_t BND = (size_t)MTOT * DD;  // 8,388,608
  float* outp  = (float*)d_out;          // [MTOT][256] (holds V until w2 overwrites)
  float* attnp = outp + BND;             // [MTOT][1024] (S, then attn)
  float* V = outp;

  _Float16* Q1 = (_Float16*)d_ws;  // 68.4 MB total ws use
  _Float16* Q2 = Q1 + BND;
  _Float16* K1 = Q2 + BND;
  _Float16* K2 = K1 + BND;
  _Float16* WT = K2 + BND;  // [5][2][65536]
  _Float16* M1 = Q1;        // reuse after topk (safe: wave reads own Q row first)
  _Float16* M2 = Q2;
  float* H = (float*)K1;    // reuse K region after topk
  _Float16* H1 = Q1;
  _Float16* H2 = Q2;

  const dim3 blk(256);

  prep_w<<<dim3(1280), blk, 0, stream>>>(wq, wk, wv, w1, w2, WT);
  gemm_qkv<<<dim3(6, 256), blk, 0, stream>>>(x, WT, bq, bk, bv, Q1, Q2, K1, K2, V);
  gemm_split<2><<<dim3(8, 256), blk, 0, stream>>>(Q1, Q2, K1, K2, adj, nullptr, attnp);
  topk_softmax_msg<<<dim3(MTOT / 4), blk, 0, stream>>>(attnp, V, Q1, Q2, K1, K2, adj, M1, M2);
  gemm_split<0><<<dim3(2, 256), blk, 0, stream>>>(M1, M2, WT + 3 * 131072, WT + 3 * 131072 + 65536,
                                                  b1, nullptr, H);
  ln_relu<<<dim3(MTOT), blk, 0, stream>>>(H, lng, lnb, H1, H2);
  gemm_split<1><<<dim3(2, 256), blk, 0, stream>>>(H1, H2, WT + 4 * 131072, WT + 4 * 131072 + 65536,
                                                  b2, V, outp);
}